// Round 12
// baseline (331.780 us; speedup 1.0000x reference)
//
#include <hip/hip_runtime.h>

// ---------------- problem constants ----------------
#define NN    10000          // nodes
#define FIN   2000           // input features
#define NH    10             // heads
#define C1    128            // layer-1 out channels per head
#define C2    64             // layer-2 out channels per head
#define HC1   1280           // NH*C1
#define HC2   640            // NH*C2
#define MP    10240          // nodes padded to 256*40
#define K1P   2016           // FIN padded to 32 multiple (63*32)
#define CAP   96             // per-node edge bucket capacity (deg~Pois(16); P(>=96)~1e-40)

typedef _Float16 f16x8 __attribute__((ext_vector_type(8)));
typedef _Float16 f16x4 __attribute__((ext_vector_type(4)));
typedef _Float16 f16x2 __attribute__((ext_vector_type(2)));
typedef float    f32x4 __attribute__((ext_vector_type(4)));

__device__ __forceinline__ float leaky(float x) { return x > 0.f ? x : 0.2f * x; }

// ---------------- prep: cast x->fp16 + transpose W1 (critical path only) ----------------
#define NCAST (2 * MP)        // 2 blocks per row (Cp4=504)
#define NW1   (63 * 40)
__global__ void k_prep(const float* __restrict__ x, _Float16* __restrict__ A1,
                       const float* __restrict__ W1, _Float16* __restrict__ W1t) {
    __shared__ float tile[32][33];
    int bid = blockIdx.x, t = threadIdx.x;
    if (bid < NCAST) {
        int r = bid >> 1;
        int c = (bid & 1) * 256 + t;
        if (c >= K1P / 4) return;
        float4 v = make_float4(0.f, 0.f, 0.f, 0.f);
        if (r < NN && c < FIN / 4) v = *(const float4*)(x + (long)r * FIN + 4 * c);
        f16x4 o = {(_Float16)v.x, (_Float16)v.y, (_Float16)v.z, (_Float16)v.w};
        *(f16x4*)(A1 + (long)r * K1P + 4 * c) = o;
        return;
    }
    int i = bid - NCAST;                   // W1 transpose: FIN x HC1 -> HC1 x K1P
    int kbase = (i % 63) * 32, nbase = (i / 63) * 32;
    int tx = t & 31, ty = t >> 5;
#pragma unroll
    for (int j = 0; j < 4; j++) {
        int k = kbase + ty + j * 8;
        float v = (k < FIN) ? W1[(long)k * HC1 + nbase + tx] : 0.0f;
        tile[ty + j * 8][tx] = v;
    }
    __syncthreads();
#pragma unroll
    for (int j = 0; j < 4; j++) {
        int n = nbase + ty + j * 8;
        W1t[(long)n * K1P + kbase + tx] = (_Float16)tile[tx][ty + j * 8];
    }
}

// ---------------- async global->LDS helper ----------------
__device__ __forceinline__ void gl2lds16(const void* g, void* l) {
    __builtin_amdgcn_global_load_lds((const __attribute__((address_space(1))) void*)g,
                                     (__attribute__((address_space(3))) void*)l, 16, 0, 0);
}

// ---------------- layer-1 GEMM: BM=256 x BN=256 (r2 config, CLOSED at ~69us) ----------------
// Side-jobs on idle CUs (bid >= nblk): bucket-fill, then dual-tile W2 transposes.
__global__ __launch_bounds__(512, 2) void k_gemm1(const _Float16* __restrict__ A,
                                                  const _Float16* __restrict__ Bt,
                                                  _Float16* __restrict__ C,
                                                  const float* __restrict__ asf,
                                                  const float* __restrict__ adf,
                                                  float* __restrict__ as,
                                                  float* __restrict__ ad,
                                                  const float* __restrict__ W2,
                                                  _Float16* __restrict__ W2t,
                                                  const int* __restrict__ ei,
                                                  int* __restrict__ cnt,
                                                  int* __restrict__ bucket,
                                                  int E, int nblk, int fillb) {
    constexpr int K    = K1P;                   // 2016
    constexpr int N    = HC1;                   // 1280
    constexpr int TBUF = 256 * 32;              // fp16 elems per A or B buffer
    __shared__ char smem[3 * TBUF * 2 * 2] __attribute__((aligned(16)));   // 96 KB
    _Float16* As = (_Float16*)smem;
    _Float16* Bs = (_Float16*)(smem + 3 * TBUF * 2);

    int bid = blockIdx.x;
    int t = threadIdx.x;
    if (bid >= nblk) {                          // ---- side jobs ----
        int sb = bid - nblk;
        if (sb < fillb) {                       // bucket fill (edges + self-loops)
            int i = sb * 512 + t;
            if (i < E + NN) {
                int s, d;
                if (i < E) { s = ei[i]; d = ei[E + i]; }
                else       { s = i - E; d = i - E; }
                int slot = atomicAdd(&cnt[d], 1);
                if (slot < CAP) bucket[d * CAP + slot] = s;
            }
            return;
        }
        // dual-tile W2 transpose: HC1 x HC2 -> HC2 x HC1 (no bounds: 1280,640 %32==0)
        int half = t >> 8, t256 = t & 255;
        int i2 = (sb - fillb) * 2 + half;       // tile 0..799
        int kbase = (i2 % 40) * 32, nbase = (i2 / 40) * 32;
        float* tile = (float*)smem + half * (32 * 33);
        int tx = t256 & 31, ty = t256 >> 5;
#pragma unroll
        for (int j = 0; j < 4; j++) {
            int k = kbase + ty + j * 8;
            tile[(ty + j * 8) * 33 + tx] = W2[(long)k * HC2 + nbase + tx];
        }
        __syncthreads();
#pragma unroll
        for (int j = 0; j < 4; j++) {
            int n = nbase + ty + j * 8;
            W2t[(long)n * HC1 + kbase + tx] = (_Float16)tile[tx * 33 + ty + j * 8];
        }
        return;
    }

    int r = bid & 7, qb = bid >> 3;
    int n_t = qb % 5;
    int m_t = r + 8 * (qb / 5);
    int m0 = m_t * 256;
    int n0 = n_t * 256;
    int lane = t & 63, wave = t >> 6;
    int wr = wave >> 2, wc = wave & 3;          // 2 x 4 wave grid
    int lrow = lane & 15, q = lane >> 4;

    f32x4 acc[8][4] = {};

    int sS[2];
#pragma unroll
    for (int i = 0; i < 2; i++) sS[i] = t + 512 * i;
    const _Float16* Ar[2];
    const _Float16* Br[2];
#pragma unroll
    for (int i = 0; i < 2; i++) {
        int row = sS[i] >> 2, gq = (sS[i] & 3) ^ ((sS[i] >> 3) & 3);
        Ar[i] = A  + (long)(m0 + row) * K + gq * 8;
        Br[i] = Bt + (long)(n0 + row) * K + gq * 8;
    }

    int aoff[8], boff[4];
#pragma unroll
    for (int i = 0; i < 8; i++) {
        int rowa = wr * 128 + i * 16 + lrow;
        aoff[i] = rowa * 32 + ((q ^ ((rowa >> 1) & 3)) << 3);
    }
#pragma unroll
    for (int i = 0; i < 4; i++) {
        int rowb = wc * 64 + i * 16 + lrow;
        boff[i] = rowb * 32 + ((q ^ ((rowb >> 1) & 3)) << 3);
    }

    auto stage = [&](int it, int buf) {
        int k0 = it << 5;
#pragma unroll
        for (int i = 0; i < 2; i++) gl2lds16(Ar[i] + k0, &As[buf * TBUF + sS[i] * 8]);
#pragma unroll
        for (int i = 0; i < 2; i++) gl2lds16(Br[i] + k0, &Bs[buf * TBUF + sS[i] * 8]);
    };

    constexpr int WVM = 0x0F70 | 4;             // vmcnt <= loads-per-stage
    int nk = K >> 5;                            // 63
    stage(0, 0);
    stage(1, 1);
    int cur = 0;
    for (int it = 0; it < nk; it++) {
        if (it + 1 < nk) __builtin_amdgcn_s_waitcnt(WVM);
        else             __builtin_amdgcn_s_waitcnt(0x0F70);
        __builtin_amdgcn_s_barrier();
        int nxt = cur + 2; if (nxt >= 3) nxt -= 3;
        if (it + 2 < nk) stage(it + 2, nxt);

        f16x8 af[8], bf[4];
#pragma unroll
        for (int i = 0; i < 8; i++) af[i] = *(const f16x8*)&As[cur * TBUF + aoff[i]];
#pragma unroll
        for (int i = 0; i < 4; i++) bf[i] = *(const f16x8*)&Bs[cur * TBUF + boff[i]];
#pragma unroll
        for (int mt = 0; mt < 8; mt++)
#pragma unroll
            for (int nt = 0; nt < 4; nt++)
                acc[mt][nt] = __builtin_amdgcn_mfma_f32_16x16x32_f16(bf[nt], af[mt], acc[mt][nt], 0, 0, 0);
        cur = (cur + 1 == 3) ? 0 : cur + 1;
    }

    // ---- C store ----
#pragma unroll
    for (int mt = 0; mt < 8; mt++) {
        int m = m0 + wr * 128 + mt * 16 + lrow;
#pragma unroll
        for (int nt = 0; nt < 4; nt++) {
            int n = n0 + wc * 64 + nt * 16 + q * 4;
            f16x4 o = {(_Float16)acc[mt][nt][0], (_Float16)acc[mt][nt][1],
                       (_Float16)acc[mt][nt][2], (_Float16)acc[mt][nt][3]};
            *(f16x4*)(C + (long)m * N + n) = o;
        }
    }

    // ---- fused logits ----
    float4 av[4], dvv[4];
#pragma unroll
    for (int nt = 0; nt < 4; nt++) {
        av[nt]  = *(const float4*)(asf + n0 + wc * 64 + nt * 16 + q * 4);
        dvv[nt] = *(const float4*)(adf + n0 + wc * 64 + nt * 16 + q * 4);
    }
    __syncthreads();                       // done reading As/Bs; reuse smem
    float* sAs = (float*)smem;             // 256*4 floats
    float* sAd = (float*)smem + 1024;
#pragma unroll
    for (int mt = 0; mt < 8; mt++) {
        float ps = 0.f, pd = 0.f;
#pragma unroll
        for (int nt = 0; nt < 4; nt++) {
            ps += acc[mt][nt][0] * av[nt].x + acc[mt][nt][1] * av[nt].y
                + acc[mt][nt][2] * av[nt].z + acc[mt][nt][3] * av[nt].w;
            pd += acc[mt][nt][0] * dvv[nt].x + acc[mt][nt][1] * dvv[nt].y
                + acc[mt][nt][2] * dvv[nt].z + acc[mt][nt][3] * dvv[nt].w;
        }
        ps += __shfl_xor(ps, 16); ps += __shfl_xor(ps, 32);
        pd += __shfl_xor(pd, 16); pd += __shfl_xor(pd, 32);
        if (q == 0) {
            int rl = wr * 128 + mt * 16 + lrow;
            sAs[rl * 4 + wc] = ps;
            sAd[rl * 4 + wc] = pd;
        }
    }
    __syncthreads();
    if (t < 256) {
        int m = m0 + t;
        if (m < NN) {
            int hb = n0 >> 7;
            as[m * NH + hb]     = sAs[t * 4 + 0] + sAs[t * 4 + 1];
            as[m * NH + hb + 1] = sAs[t * 4 + 2] + sAs[t * 4 + 3];
            ad[m * NH + hb]     = sAd[t * 4 + 0] + sAd[t * 4 + 1];
            ad[m * NH + hb + 1] = sAd[t * 4 + 2] + sAd[t * 4 + 3];
        }
    }
}

// ---------------- generic fp16 MFMA GEMM (layer 2), BM=32*MFRAG x BN=128 ----------------
template<int MFRAG>
__global__ __launch_bounds__(256, 3) void k_gemm(const _Float16* __restrict__ A,
                                                 const _Float16* __restrict__ Bt,
                                                 _Float16* __restrict__ C, int K, int N,
                                                 int NTN,
                                                 const float* __restrict__ asf,
                                                 const float* __restrict__ adf,
                                                 float* __restrict__ as,
                                                 float* __restrict__ ad,
                                                 int headw) {
    constexpr int BM   = MFRAG * 32;
    constexpr int ABUF = BM * 32;
    constexpr int ASL  = BM / 64;
    constexpr int WVM  = 0x0F70 | (ASL + 2);
    __shared__ char smem[3 * ABUF * 2 + 3 * 8192] __attribute__((aligned(16)));
    _Float16* As = (_Float16*)smem;
    _Float16* Bs = (_Float16*)(smem + 3 * ABUF * 2);

    int bid = blockIdx.x;
    int r = bid & 7, qb = bid >> 3;
    int n_t = qb % NTN;
    int m_t = r + 8 * (qb / NTN);
    int m0 = m_t * BM;
    int n0 = n_t * 128;
    int t = threadIdx.x;
    int lane = t & 63, wave = t >> 6;
    int wr = wave >> 1, wc = wave & 1;
    int lrow = lane & 15, q = lane >> 4;

    f32x4 acc[MFRAG][4] = {};

    int sA[ASL], sB[2];
#pragma unroll
    for (int i = 0; i < ASL; i++) sA[i] = t + 256 * i;
#pragma unroll
    for (int i = 0; i < 2; i++) sB[i] = t + 256 * i;
    const _Float16* Ar[ASL];
    const _Float16* Br[2];
#pragma unroll
    for (int i = 0; i < ASL; i++) {
        int row = sA[i] >> 2, gq = (sA[i] & 3) ^ ((sA[i] >> 3) & 3);
        Ar[i] = A + (long)(m0 + row) * K + gq * 8;
    }
#pragma unroll
    for (int i = 0; i < 2; i++) {
        int row = sB[i] >> 2, gq = (sB[i] & 3) ^ ((sB[i] >> 3) & 3);
        Br[i] = Bt + (long)(n0 + row) * K + gq * 8;
    }

    int aoff[MFRAG], boff[4];
#pragma unroll
    for (int i = 0; i < MFRAG; i++) {
        int rowa = wr * (MFRAG * 16) + i * 16 + lrow;
        aoff[i] = rowa * 32 + ((q ^ ((rowa >> 1) & 3)) << 3);
    }
#pragma unroll
    for (int i = 0; i < 4; i++) {
        int rowb = wc * 64 + i * 16 + lrow;
        boff[i] = rowb * 32 + ((q ^ ((rowb >> 1) & 3)) << 3);
    }

    auto stage = [&](int it, int buf) {
        int k0 = it << 5;
#pragma unroll
        for (int i = 0; i < ASL; i++) gl2lds16(Ar[i] + k0, &As[buf * ABUF + sA[i] * 8]);
#pragma unroll
        for (int i = 0; i < 2; i++) gl2lds16(Br[i] + k0, &Bs[buf * 4096 + sB[i] * 8]);
    };

    int nk = K >> 5;
    stage(0, 0);
    stage(1, 1);
    int cur = 0;
    for (int it = 0; it < nk; it++) {
        if (it + 1 < nk) __builtin_amdgcn_s_waitcnt(WVM);
        else             __builtin_amdgcn_s_waitcnt(0x0F70);
        __builtin_amdgcn_s_barrier();
        int nxt = cur + 2; if (nxt >= 3) nxt -= 3;
        if (it + 2 < nk) stage(it + 2, nxt);

        f16x8 af[MFRAG], bf[4];
#pragma unroll
        for (int i = 0; i < MFRAG; i++) af[i] = *(const f16x8*)&As[cur * ABUF + aoff[i]];
#pragma unroll
        for (int i = 0; i < 4; i++) bf[i] = *(const f16x8*)&Bs[cur * 4096 + boff[i]];
#pragma unroll
        for (int mt = 0; mt < MFRAG; mt++)
#pragma unroll
            for (int nt = 0; nt < 4; nt++)
                acc[mt][nt] = __builtin_amdgcn_mfma_f32_16x16x32_f16(bf[nt], af[mt], acc[mt][nt], 0, 0, 0);
        cur = (cur + 1 == 3) ? 0 : cur + 1;
    }

#pragma unroll
    for (int mt = 0; mt < MFRAG; mt++) {
        int m = m0 + wr * (MFRAG * 16) + mt * 16 + lrow;
#pragma unroll
        for (int nt = 0; nt < 4; nt++) {
            int n = n0 + wc * 64 + nt * 16 + q * 4;
            f16x4 o = {(_Float16)acc[mt][nt][0], (_Float16)acc[mt][nt][1],
                       (_Float16)acc[mt][nt][2], (_Float16)acc[mt][nt][3]};
            *(f16x4*)(C + (long)m * N + n) = o;
        }
    }

    float4 av[4], dvv[4];
#pragma unroll
    for (int nt = 0; nt < 4; nt++) {
        av[nt]  = *(const float4*)(asf + n0 + wc * 64 + nt * 16 + q * 4);
        dvv[nt] = *(const float4*)(adf + n0 + wc * 64 + nt * 16 + q * 4);
    }
    __syncthreads();
    float* sAs = (float*)smem;
    float* sAd = (float*)smem + BM * 2;
#pragma unroll
    for (int mt = 0; mt < MFRAG; mt++) {
        float ps = 0.f, pd = 0.f;
#pragma unroll
        for (int nt = 0; nt < 4; nt++) {
            ps += acc[mt][nt][0] * av[nt].x + acc[mt][nt][1] * av[nt].y
                + acc[mt][nt][2] * av[nt].z + acc[mt][nt][3] * av[nt].w;
            pd += acc[mt][nt][0] * dvv[nt].x + acc[mt][nt][1] * dvv[nt].y
                + acc[mt][nt][2] * dvv[nt].z + acc[mt][nt][3] * dvv[nt].w;
        }
        ps += __shfl_xor(ps, 16); ps += __shfl_xor(ps, 32);
        pd += __shfl_xor(pd, 16); pd += __shfl_xor(pd, 32);
        if (q == 0) {
            int rl = wr * (MFRAG * 16) + mt * 16 + lrow;
            sAs[rl * 2 + wc] = ps;
            sAd[rl * 2 + wc] = pd;
        }
    }
    __syncthreads();
    if (t < BM) {
        int m = m0 + t;
        if (m < NN) {
            int hb = n0 / headw;
            if (headw == 128) {
                as[m * NH + hb] = sAs[t * 2] + sAs[t * 2 + 1];
                ad[m * NH + hb] = sAd[t * 2] + sAd[t * 2 + 1];
            } else {
                as[m * NH + hb]     = sAs[t * 2];
                as[m * NH + hb + 1] = sAs[t * 2 + 1];
                ad[m * NH + hb]     = sAd[t * 2];
                ad[m * NH + hb + 1] = sAd[t * 2 + 1];
            }
        }
    }
}

// ---------------- layer-1 agg: dual-row-group gather (2x160 thr, f16x8) ----------------
// r11 post-mortem: same gather bytes, half the loop trips, 16 B/lane loads.
// Groups handle even/odd rows; cross-group combine via LDS.
__global__ __launch_bounds__(320) void k_agg1(const int* __restrict__ cnt,
                                              const int* __restrict__ bucket,
                                              const float* __restrict__ as,
                                              const float* __restrict__ ad,
                                              const _Float16* __restrict__ h,
                                              const float* __restrict__ bias,
                                              _Float16* __restrict__ A2) {
    __shared__ int sidx[64];
    __shared__ float sal[64 * NH];
    __shared__ float sacc[2][HC1];
    int n = blockIdx.x, t = threadIdx.x;
    if (n >= NN) {
        f16x4 z = {(_Float16)0.f, (_Float16)0.f, (_Float16)0.f, (_Float16)0.f};
        *(f16x4*)(A2 + (long)n * HC1 + 4 * t) = z;
        return;
    }
    int deg = min(cnt[n], CAP);
    const int* bkt = bucket + (long)n * CAP;
    int w = t >> 6, lane = t & 63;
    int g = (t >= 160) ? 1 : 0;            // row group
    int c = t - 160 * g;                   // 0..159: channels 8c..8c+7
    int hd8 = c >> 4;                      // head of this channel octet
    float acc8[8] = {};

    if (deg <= 64) {
        int src = (lane < deg) ? bkt[lane] : 0;
        float2 adv = *(const float2*)(ad + n * NH + 2 * w);
        float x0 = 0.f, x1 = 0.f;
        if (lane < deg) {
            float2 avv = *(const float2*)(as + (long)src * NH + 2 * w);
            x0 = __expf(leaky(avv.x + adv.x));
            x1 = __expf(leaky(avv.y + adv.y));
        }
        float s0 = x0, s1 = x1;
        for (int m = 32; m; m >>= 1) {
            s0 += __shfl_xor(s0, m);
            s1 += __shfl_xor(s1, m);
        }
        if (lane < deg) {
            sal[lane * NH + 2 * w]     = x0 / (s0 + 1e-16f);
            sal[lane * NH + 2 * w + 1] = x1 / (s1 + 1e-16f);
            if (w == 0) sidx[lane] = src;
        }
        __syncthreads();
        int j = 0;
        for (; j + 8 <= deg; j += 8) {            // 4 rows/group in flight
            int r0 = j + g, r1 = j + 2 + g, r2 = j + 4 + g, r3 = j + 6 + g;
            int s0i = sidx[r0], s1i = sidx[r1], s2i = sidx[r2], s3i = sidx[r3];
            float a0 = sal[r0 * NH + hd8], a1 = sal[r1 * NH + hd8];
            float a2 = sal[r2 * NH + hd8], a3 = sal[r3 * NH + hd8];
            f16x8 v0 = *(const f16x8*)(h + (long)s0i * HC1 + 8 * c);
            f16x8 v1 = *(const f16x8*)(h + (long)s1i * HC1 + 8 * c);
            f16x8 v2 = *(const f16x8*)(h + (long)s2i * HC1 + 8 * c);
            f16x8 v3 = *(const f16x8*)(h + (long)s3i * HC1 + 8 * c);
#pragma unroll
            for (int i = 0; i < 8; i++)
                acc8[i] += a0 * (float)v0[i] + a1 * (float)v1[i]
                         + a2 * (float)v2[i] + a3 * (float)v3[i];
        }
        for (; j + 2 <= deg; j += 2) {
            int rr = j + g;
            int ss = sidx[rr];
            float aa = sal[rr * NH + hd8];
            f16x8 v = *(const f16x8*)(h + (long)ss * HC1 + 8 * c);
#pragma unroll
            for (int i = 0; i < 8; i++) acc8[i] += aa * (float)v[i];
        }
        if (j < deg && g == 0) {               // odd leftover row
            int ss = sidx[j];
            float aa = sal[j * NH + hd8];
            f16x8 v = *(const f16x8*)(h + (long)ss * HC1 + 8 * c);
#pragma unroll
            for (int i = 0; i < 8; i++) acc8[i] += aa * (float)v[i];
        }
    } else {
        float2 adv = *(const float2*)(ad + n * NH + 2 * w);
        float s0 = 0.f, s1 = 0.f;
        for (int j = lane; j < deg; j += 64) {
            float2 avv = *(const float2*)(as + (long)bkt[j] * NH + 2 * w);
            s0 += __expf(leaky(avv.x + adv.x));
            s1 += __expf(leaky(avv.y + adv.y));
        }
        for (int m = 32; m; m >>= 1) {
            s0 += __shfl_xor(s0, m);
            s1 += __shfl_xor(s1, m);
        }
        float i0 = 1.f / (s0 + 1e-16f), i1 = 1.f / (s1 + 1e-16f);
        for (int c0 = 0; c0 < deg; c0 += 64) {
            int cn = min(64, deg - c0);
            __syncthreads();
            if (lane < cn) {
                int src = bkt[c0 + lane];
                float2 avv = *(const float2*)(as + (long)src * NH + 2 * w);
                sal[lane * NH + 2 * w]     = __expf(leaky(avv.x + adv.x)) * i0;
                sal[lane * NH + 2 * w + 1] = __expf(leaky(avv.y + adv.y)) * i1;
                if (w == 0) sidx[lane] = src;
            }
            __syncthreads();
            int jj = 0;
            for (; jj + 2 <= cn; jj += 2) {
                int rr = jj + g;
                int ss = sidx[rr];
                float aa = sal[rr * NH + hd8];
                f16x8 v = *(const f16x8*)(h + (long)ss * HC1 + 8 * c);
#pragma unroll
                for (int i = 0; i < 8; i++) acc8[i] += aa * (float)v[i];
            }
            if (jj < cn && g == 0) {
                int ss = sidx[jj];
                float aa = sal[jj * NH + hd8];
                f16x8 v = *(const f16x8*)(h + (long)ss * HC1 + 8 * c);
#pragma unroll
                for (int i = 0; i < 8; i++) acc8[i] += aa * (float)v[i];
            }
        }
    }
    // combine groups + bias + relu + store
#pragma unroll
    for (int i = 0; i < 8; i++) sacc[g][8 * c + i] = acc8[i];
    __syncthreads();
    f16x4 o;
#pragma unroll
    for (int i = 0; i < 4; i++) {
        int ch = 4 * t + i;
        float x = sacc[0][ch] + sacc[1][ch] + bias[ch];
        o[i] = (_Float16)(x > 0.f ? x : 0.f);
    }
    *(f16x4*)(A2 + (long)n * HC1 + 4 * t) = o;
}

// ---------------- layer-2 agg: dual-row-group gather (2x160 thr, f16x4) + head mean ----------------
__global__ __launch_bounds__(320) void k_agg2(const int* __restrict__ cnt,
                                              const int* __restrict__ bucket,
                                              const float* __restrict__ as,
                                              const float* __restrict__ ad,
                                              const _Float16* __restrict__ h,
                                              const float* __restrict__ bias,
                                              float* __restrict__ out) {
    __shared__ int sidx[64];
    __shared__ float sal[64 * NH];
    __shared__ float sacc[2][HC2];
    int n = blockIdx.x, t = threadIdx.x;
    int deg = min(cnt[n], CAP);
    const int* bkt = bucket + (long)n * CAP;
    int w = t >> 6, lane = t & 63;
    int g = (t >= 160) ? 1 : 0;            // row group
    int c = t - 160 * g;                   // 0..159: channels 4c..4c+3
    int hd4 = c >> 4;                      // head of this channel quad (4c/64)
    float acc4[4] = {};

    if (deg <= 64) {
        int src = (lane < deg) ? bkt[lane] : 0;
        float2 adv = *(const float2*)(ad + n * NH + 2 * w);
        float x0 = 0.f, x1 = 0.f;
        if (lane < deg) {
            float2 avv = *(const float2*)(as + (long)src * NH + 2 * w);
            x0 = __expf(leaky(avv.x + adv.x));
            x1 = __expf(leaky(avv.y + adv.y));
        }
        float s0 = x0, s1 = x1;
        for (int m = 32; m; m >>= 1) {
            s0 += __shfl_xor(s0, m);
            s1 += __shfl_xor(s1, m);
        }
        if (lane < deg) {
            sal[lane * NH + 2 * w]     = x0 / (s0 + 1e-16f);
            sal[lane * NH + 2 * w + 1] = x1 / (s1 + 1e-16f);
            if (w == 0) sidx[lane] = src;
        }
        __syncthreads();
        int j = 0;
        for (; j + 8 <= deg; j += 8) {            // 4 rows/group in flight
            int r0 = j + g, r1 = j + 2 + g, r2 = j + 4 + g, r3 = j + 6 + g;
            int s0i = sidx[r0], s1i = sidx[r1], s2i = sidx[r2], s3i = sidx[r3];
            float a0 = sal[r0 * NH + hd4], a1 = sal[r1 * NH + hd4];
            float a2 = sal[r2 * NH + hd4], a3 = sal[r3 * NH + hd4];
            f16x4 v0 = *(const f16x4*)(h + (long)s0i * HC2 + 4 * c);
            f16x4 v1 = *(const f16x4*)(h + (long)s1i * HC2 + 4 * c);
            f16x4 v2 = *(const f16x4*)(h + (long)s2i * HC2 + 4 * c);
            f16x4 v3 = *(const f16x4*)(h + (long)s3i * HC2 + 4 * c);
#pragma unroll
            for (int i = 0; i < 4; i++)
                acc4[i] += a0 * (float)v0[i] + a1 * (float)v1[i]
                         + a2 * (float)v2[i] + a3 * (float)v3[i];
        }
        for (; j + 2 <= deg; j += 2) {
            int rr = j + g;
            int ss = sidx[rr];
            float aa = sal[rr * NH + hd4];
            f16x4 v = *(const f16x4*)(h + (long)ss * HC2 + 4 * c);
#pragma unroll
            for (int i = 0; i < 4; i++) acc4[i] += aa * (float)v[i];
        }
        if (j < deg && g == 0) {
            int ss = sidx[j];
            float aa = sal[j * NH + hd4];
            f16x4 v = *(const f16x4*)(h + (long)ss * HC2 + 4 * c);
#pragma unroll
            for (int i = 0; i < 4; i++) acc4[i] += aa * (float)v[i];
        }
    } else {
        float2 adv = *(const float2*)(ad + n * NH + 2 * w);
        float s0 = 0.f, s1 = 0.f;
        for (int j = lane; j < deg; j += 64) {
            float2 avv = *(const float2*)(as + (long)bkt[j] * NH + 2 * w);
            s0 += __expf(leaky(avv.x + adv.x));
            s1 += __expf(leaky(avv.y + adv.y));
        }
        for (int m = 32; m; m >>= 1) {
            s0 += __shfl_xor(s0, m);
            s1 += __shfl_xor(s1, m);
        }
        float i0 = 1.f / (s0 + 1e-16f), i1 = 1.f / (s1 + 1e-16f);
        for (int c0 = 0; c0 < deg; c0 += 64) {
            int cn = min(64, deg - c0);
            __syncthreads();
            if (lane < cn) {
                int src = bkt[c0 + lane];
                float2 avv = *(const float2*)(as + (long)src * NH + 2 * w);
                sal[lane * NH + 2 * w]     = __expf(leaky(avv.x + adv.x)) * i0;
                sal[lane * NH + 2 * w + 1] = __expf(leaky(avv.y + adv.y)) * i1;
                if (w == 0) sidx[lane] = src;
            }
            __syncthreads();
            int jj = 0;
            for (; jj + 2 <= cn; jj += 2) {
                int rr = jj + g;
                int ss = sidx[rr];
                float aa = sal[rr * NH + hd4];
                f16x4 v = *(const f16x4*)(h + (long)ss * HC2 + 4 * c);
#pragma unroll
                for (int i = 0; i < 4; i++) acc4[i] += aa * (float)v[i];
            }
            if (jj < cn && g == 0) {
                int ss = sidx[jj];
                float aa = sal[jj * NH + hd4];
                f16x4 v = *(const f16x4*)(h + (long)ss * HC2 + 4 * c);
#pragma unroll
                for (int i = 0; i < 4; i++) acc4[i] += aa * (float)v[i];
            }
        }
    }
    // combine groups, then head-mean
#pragma unroll
    for (int i = 0; i < 4; i++) sacc[g][4 * c + i] = acc4[i];
    __syncthreads();
    if (t < 320) {                              // fold group1 into group0 (2 ch/thread)
        int ch = 2 * t;
        sacc[0][ch]     += sacc[1][ch];
        sacc[0][ch + 1] += sacc[1][ch + 1];
    }
    __syncthreads();
    if (t < C2) {
        float s = 0.f;
#pragma unroll
        for (int hh = 0; hh < NH; hh++) s += sacc[0][hh * C2 + t];
        s = s * 0.1f + bias[t];
        out[(long)n * C2 + t] = s > 0.f ? s : 0.f;
    }
}

// ---------------- host ----------------
extern "C" void kernel_launch(void* const* d_in, const int* in_sizes, int n_in,
                              void* d_out, int out_size, void* d_ws, size_t ws_size,
                              hipStream_t stream) {
    const float* x      = (const float*)d_in[0];
    const int*   ei     = (const int*)d_in[1];
    const float* W1     = (const float*)d_in[2];
    const float* asrc1  = (const float*)d_in[3];
    const float* adst1  = (const float*)d_in[4];
    const float* b1     = (const float*)d_in[5];
    const float* W2     = (const float*)d_in[6];
    const float* asrc2  = (const float*)d_in[7];
    const float* adst2  = (const float*)d_in[8];
    const float* b2     = (const float*)d_in[9];
    float* out = (float*)d_out;
    const int E  = in_sizes[1] / 2;

    char* base = (char*)d_ws;
    size_t o = 0;
    auto alloc = [&](size_t bytes) { size_t r = o; o += (bytes + 255) & ~(size_t)255; return r; };
    _Float16* A1    = (_Float16*)(base + alloc((size_t)MP * K1P * 2));
    _Float16* W1t   = (_Float16*)(base + alloc((size_t)HC1 * K1P * 2));
    _Float16* A2    = (_Float16*)(base + alloc((size_t)MP * HC1 * 2));
    _Float16* W2t   = (_Float16*)(base + alloc((size_t)HC2 * HC1 * 2));
    _Float16* h1pre = (_Float16*)(base + alloc((size_t)MP * HC1 * 2));
    _Float16* h2pre = (_Float16*)(base + alloc((size_t)MP * HC2 * 2));
    float* as1      = (float*)(base + alloc((size_t)NN * NH * 4));
    float* ad1      = (float*)(base + alloc((size_t)NN * NH * 4));
    float* as2      = (float*)(base + alloc((size_t)NN * NH * 4));
    float* ad2      = (float*)(base + alloc((size_t)NN * NH * 4));
    int* cnt        = (int*)(base + alloc((size_t)NN * 4));
    int* bucket     = (int*)(base + alloc((size_t)NN * CAP * 4));
    (void)ws_size; (void)n_in; (void)out_size;

    const int FILLB = (E + NN + 511) / 512;            // 512-thr fill side blocks
    const int W2TB  = (40 * 20) / 2;                   // 400 dual-tile W2t side blocks
    const int G1 = 8 * (MP / 256 / 8) * (HC1 / 256);   // 200 gemm1 blocks (256x256)
    const int G2 = 8 * (MP / 128 / 8) * (HC2 / 128);   // 400 gemm2 blocks (MFRAG=4)

    // ---- zero cnt; prep = cast + W1 transpose only ----
    hipMemsetAsync(cnt, 0, (size_t)NN * 4, stream);
    k_prep<<<NCAST + NW1, 256, 0, stream>>>(x, A1, W1, W1t);
    // ---- layer 1 GEMM + side-jobs (bucket fill, W2 transpose) on idle CUs ----
    k_gemm1<<<G1 + FILLB + W2TB, 512, 0, stream>>>(A1, W1t, h1pre, asrc1, adst1, as1, ad1,
                                                   W2, W2t, ei, cnt, bucket, E, G1, FILLB);
    // ---- layer 1 agg ----
    k_agg1<<<MP, 320, 0, stream>>>(cnt, bucket, as1, ad1, h1pre, b1, A2);
    // ---- layer 2 GEMM (MFRAG=4, 400 blocks -> 2-3/CU service regime) ----
    k_gemm<4><<<G2, 256, 0, stream>>>(A2, W2t, h2pre, HC1, HC2, HC2 / 128,
                                      asrc2, adst2, as2, ad2, C2);
    // ---- layer 2 agg ----
    k_agg2<<<NN, 320, 0, stream>>>(cnt, bucket, as2, ad2, h2pre, b2, out);
}

// Round 13
// 327.722 us; speedup vs baseline: 1.0124x; 1.0124x over previous
//
#include <hip/hip_runtime.h>

// ---------------- problem constants ----------------
#define NN    10000          // nodes
#define FIN   2000           // input features
#define NH    10             // heads
#define C1    128            // layer-1 out channels per head
#define C2    64             // layer-2 out channels per head
#define HC1   1280           // NH*C1
#define HC2   640            // NH*C2
#define MP    10240          // nodes padded to 256*40
#define K1P   2016           // FIN padded to 32 multiple (63*32)
#define CAP   96             // per-node edge bucket capacity (deg~Pois(16); P(>=96)~1e-40)

typedef _Float16 f16x8 __attribute__((ext_vector_type(8)));
typedef _Float16 f16x4 __attribute__((ext_vector_type(4)));
typedef _Float16 f16x2 __attribute__((ext_vector_type(2)));
typedef float    f32x4 __attribute__((ext_vector_type(4)));

__device__ __forceinline__ float leaky(float x) { return x > 0.f ? x : 0.2f * x; }

// ---------------- prep: cast x->fp16 + transpose W1 (critical path only) ----------------
#define NCAST (2 * MP)        // 2 blocks per row (Cp4=504)
#define NW1   (63 * 40)
__global__ void k_prep(const float* __restrict__ x, _Float16* __restrict__ A1,
                       const float* __restrict__ W1, _Float16* __restrict__ W1t) {
    __shared__ float tile[32][33];
    int bid = blockIdx.x, t = threadIdx.x;
    if (bid < NCAST) {
        int r = bid >> 1;
        int c = (bid & 1) * 256 + t;
        if (c >= K1P / 4) return;
        float4 v = make_float4(0.f, 0.f, 0.f, 0.f);
        if (r < NN && c < FIN / 4) v = *(const float4*)(x + (long)r * FIN + 4 * c);
        f16x4 o = {(_Float16)v.x, (_Float16)v.y, (_Float16)v.z, (_Float16)v.w};
        *(f16x4*)(A1 + (long)r * K1P + 4 * c) = o;
        return;
    }
    int i = bid - NCAST;                   // W1 transpose: FIN x HC1 -> HC1 x K1P
    int kbase = (i % 63) * 32, nbase = (i / 63) * 32;
    int tx = t & 31, ty = t >> 5;
#pragma unroll
    for (int j = 0; j < 4; j++) {
        int k = kbase + ty + j * 8;
        float v = (k < FIN) ? W1[(long)k * HC1 + nbase + tx] : 0.0f;
        tile[ty + j * 8][tx] = v;
    }
    __syncthreads();
#pragma unroll
    for (int j = 0; j < 4; j++) {
        int n = nbase + ty + j * 8;
        W1t[(long)n * K1P + kbase + tx] = (_Float16)tile[tx][ty + j * 8];
    }
}

// ---------------- async global->LDS helper ----------------
__device__ __forceinline__ void gl2lds16(const void* g, void* l) {
    __builtin_amdgcn_global_load_lds((const __attribute__((address_space(1))) void*)g,
                                     (__attribute__((address_space(3))) void*)l, 16, 0, 0);
}

// ---------------- layer-1 GEMM: BM=256 x BN=256 (r2 config, CLOSED at ~69us) ----------------
// Side-jobs on idle CUs (bid >= nblk): bucket-fill, then dual-tile W2 transposes.
__global__ __launch_bounds__(512, 2) void k_gemm1(const _Float16* __restrict__ A,
                                                  const _Float16* __restrict__ Bt,
                                                  _Float16* __restrict__ C,
                                                  const float* __restrict__ asf,
                                                  const float* __restrict__ adf,
                                                  float* __restrict__ as,
                                                  float* __restrict__ ad,
                                                  const float* __restrict__ W2,
                                                  _Float16* __restrict__ W2t,
                                                  const int* __restrict__ ei,
                                                  int* __restrict__ cnt,
                                                  int* __restrict__ bucket,
                                                  int E, int nblk, int fillb) {
    constexpr int K    = K1P;                   // 2016
    constexpr int N    = HC1;                   // 1280
    constexpr int TBUF = 256 * 32;              // fp16 elems per A or B buffer
    __shared__ char smem[3 * TBUF * 2 * 2] __attribute__((aligned(16)));   // 96 KB
    _Float16* As = (_Float16*)smem;
    _Float16* Bs = (_Float16*)(smem + 3 * TBUF * 2);

    int bid = blockIdx.x;
    int t = threadIdx.x;
    if (bid >= nblk) {                          // ---- side jobs ----
        int sb = bid - nblk;
        if (sb < fillb) {                       // bucket fill (edges + self-loops)
            int i = sb * 512 + t;
            if (i < E + NN) {
                int s, d;
                if (i < E) { s = ei[i]; d = ei[E + i]; }
                else       { s = i - E; d = i - E; }
                int slot = atomicAdd(&cnt[d], 1);
                if (slot < CAP) bucket[d * CAP + slot] = s;
            }
            return;
        }
        // dual-tile W2 transpose: HC1 x HC2 -> HC2 x HC1 (no bounds: 1280,640 %32==0)
        int half = t >> 8, t256 = t & 255;
        int i2 = (sb - fillb) * 2 + half;       // tile 0..799
        int kbase = (i2 % 40) * 32, nbase = (i2 / 40) * 32;
        float* tile = (float*)smem + half * (32 * 33);
        int tx = t256 & 31, ty = t256 >> 5;
#pragma unroll
        for (int j = 0; j < 4; j++) {
            int k = kbase + ty + j * 8;
            tile[(ty + j * 8) * 33 + tx] = W2[(long)k * HC2 + nbase + tx];
        }
        __syncthreads();
#pragma unroll
        for (int j = 0; j < 4; j++) {
            int n = nbase + ty + j * 8;
            W2t[(long)n * HC1 + kbase + tx] = (_Float16)tile[tx * 33 + ty + j * 8];
        }
        return;
    }

    int r = bid & 7, qb = bid >> 3;
    int n_t = qb % 5;
    int m_t = r + 8 * (qb / 5);
    int m0 = m_t * 256;
    int n0 = n_t * 256;
    int lane = t & 63, wave = t >> 6;
    int wr = wave >> 2, wc = wave & 3;          // 2 x 4 wave grid
    int lrow = lane & 15, q = lane >> 4;

    f32x4 acc[8][4] = {};

    int sS[2];
#pragma unroll
    for (int i = 0; i < 2; i++) sS[i] = t + 512 * i;
    const _Float16* Ar[2];
    const _Float16* Br[2];
#pragma unroll
    for (int i = 0; i < 2; i++) {
        int row = sS[i] >> 2, gq = (sS[i] & 3) ^ ((sS[i] >> 3) & 3);
        Ar[i] = A  + (long)(m0 + row) * K + gq * 8;
        Br[i] = Bt + (long)(n0 + row) * K + gq * 8;
    }

    int aoff[8], boff[4];
#pragma unroll
    for (int i = 0; i < 8; i++) {
        int rowa = wr * 128 + i * 16 + lrow;
        aoff[i] = rowa * 32 + ((q ^ ((rowa >> 1) & 3)) << 3);
    }
#pragma unroll
    for (int i = 0; i < 4; i++) {
        int rowb = wc * 64 + i * 16 + lrow;
        boff[i] = rowb * 32 + ((q ^ ((rowb >> 1) & 3)) << 3);
    }

    auto stage = [&](int it, int buf) {
        int k0 = it << 5;
#pragma unroll
        for (int i = 0; i < 2; i++) gl2lds16(Ar[i] + k0, &As[buf * TBUF + sS[i] * 8]);
#pragma unroll
        for (int i = 0; i < 2; i++) gl2lds16(Br[i] + k0, &Bs[buf * TBUF + sS[i] * 8]);
    };

    constexpr int WVM = 0x0F70 | 4;             // vmcnt <= loads-per-stage
    int nk = K >> 5;                            // 63
    stage(0, 0);
    stage(1, 1);
    int cur = 0;
    for (int it = 0; it < nk; it++) {
        if (it + 1 < nk) __builtin_amdgcn_s_waitcnt(WVM);
        else             __builtin_amdgcn_s_waitcnt(0x0F70);
        __builtin_amdgcn_s_barrier();
        int nxt = cur + 2; if (nxt >= 3) nxt -= 3;
        if (it + 2 < nk) stage(it + 2, nxt);

        f16x8 af[8], bf[4];
#pragma unroll
        for (int i = 0; i < 8; i++) af[i] = *(const f16x8*)&As[cur * TBUF + aoff[i]];
#pragma unroll
        for (int i = 0; i < 4; i++) bf[i] = *(const f16x8*)&Bs[cur * TBUF + boff[i]];
#pragma unroll
        for (int mt = 0; mt < 8; mt++)
#pragma unroll
            for (int nt = 0; nt < 4; nt++)
                acc[mt][nt] = __builtin_amdgcn_mfma_f32_16x16x32_f16(bf[nt], af[mt], acc[mt][nt], 0, 0, 0);
        cur = (cur + 1 == 3) ? 0 : cur + 1;
    }

    // ---- C store ----
#pragma unroll
    for (int mt = 0; mt < 8; mt++) {
        int m = m0 + wr * 128 + mt * 16 + lrow;
#pragma unroll
        for (int nt = 0; nt < 4; nt++) {
            int n = n0 + wc * 64 + nt * 16 + q * 4;
            f16x4 o = {(_Float16)acc[mt][nt][0], (_Float16)acc[mt][nt][1],
                       (_Float16)acc[mt][nt][2], (_Float16)acc[mt][nt][3]};
            *(f16x4*)(C + (long)m * N + n) = o;
        }
    }

    // ---- fused logits ----
    float4 av[4], dvv[4];
#pragma unroll
    for (int nt = 0; nt < 4; nt++) {
        av[nt]  = *(const float4*)(asf + n0 + wc * 64 + nt * 16 + q * 4);
        dvv[nt] = *(const float4*)(adf + n0 + wc * 64 + nt * 16 + q * 4);
    }
    __syncthreads();                       // done reading As/Bs; reuse smem
    float* sAs = (float*)smem;             // 256*4 floats
    float* sAd = (float*)smem + 1024;
#pragma unroll
    for (int mt = 0; mt < 8; mt++) {
        float ps = 0.f, pd = 0.f;
#pragma unroll
        for (int nt = 0; nt < 4; nt++) {
            ps += acc[mt][nt][0] * av[nt].x + acc[mt][nt][1] * av[nt].y
                + acc[mt][nt][2] * av[nt].z + acc[mt][nt][3] * av[nt].w;
            pd += acc[mt][nt][0] * dvv[nt].x + acc[mt][nt][1] * dvv[nt].y
                + acc[mt][nt][2] * dvv[nt].z + acc[mt][nt][3] * dvv[nt].w;
        }
        ps += __shfl_xor(ps, 16); ps += __shfl_xor(ps, 32);
        pd += __shfl_xor(pd, 16); pd += __shfl_xor(pd, 32);
        if (q == 0) {
            int rl = wr * 128 + mt * 16 + lrow;
            sAs[rl * 4 + wc] = ps;
            sAd[rl * 4 + wc] = pd;
        }
    }
    __syncthreads();
    if (t < 256) {
        int m = m0 + t;
        if (m < NN) {
            int hb = n0 >> 7;
            as[m * NH + hb]     = sAs[t * 4 + 0] + sAs[t * 4 + 1];
            as[m * NH + hb + 1] = sAs[t * 4 + 2] + sAs[t * 4 + 3];
            ad[m * NH + hb]     = sAd[t * 4 + 0] + sAd[t * 4 + 1];
            ad[m * NH + hb + 1] = sAd[t * 4 + 2] + sAd[t * 4 + 3];
        }
    }
}

// ---------------- generic fp16 MFMA GEMM (layer 2), BM=32*MFRAG x BN=128 ----------------
template<int MFRAG>
__global__ __launch_bounds__(256, 3) void k_gemm(const _Float16* __restrict__ A,
                                                 const _Float16* __restrict__ Bt,
                                                 _Float16* __restrict__ C, int K, int N,
                                                 int NTN,
                                                 const float* __restrict__ asf,
                                                 const float* __restrict__ adf,
                                                 float* __restrict__ as,
                                                 float* __restrict__ ad,
                                                 int headw) {
    constexpr int BM   = MFRAG * 32;
    constexpr int ABUF = BM * 32;
    constexpr int ASL  = BM / 64;
    constexpr int WVM  = 0x0F70 | (ASL + 2);
    __shared__ char smem[3 * ABUF * 2 + 3 * 8192] __attribute__((aligned(16)));
    _Float16* As = (_Float16*)smem;
    _Float16* Bs = (_Float16*)(smem + 3 * ABUF * 2);

    int bid = blockIdx.x;
    int r = bid & 7, qb = bid >> 3;
    int n_t = qb % NTN;
    int m_t = r + 8 * (qb / NTN);
    int m0 = m_t * BM;
    int n0 = n_t * 128;
    int t = threadIdx.x;
    int lane = t & 63, wave = t >> 6;
    int wr = wave >> 1, wc = wave & 1;
    int lrow = lane & 15, q = lane >> 4;

    f32x4 acc[MFRAG][4] = {};

    int sA[ASL], sB[2];
#pragma unroll
    for (int i = 0; i < ASL; i++) sA[i] = t + 256 * i;
#pragma unroll
    for (int i = 0; i < 2; i++) sB[i] = t + 256 * i;
    const _Float16* Ar[ASL];
    const _Float16* Br[2];
#pragma unroll
    for (int i = 0; i < ASL; i++) {
        int row = sA[i] >> 2, gq = (sA[i] & 3) ^ ((sA[i] >> 3) & 3);
        Ar[i] = A + (long)(m0 + row) * K + gq * 8;
    }
#pragma unroll
    for (int i = 0; i < 2; i++) {
        int row = sB[i] >> 2, gq = (sB[i] & 3) ^ ((sB[i] >> 3) & 3);
        Br[i] = Bt + (long)(n0 + row) * K + gq * 8;
    }

    int aoff[MFRAG], boff[4];
#pragma unroll
    for (int i = 0; i < MFRAG; i++) {
        int rowa = wr * (MFRAG * 16) + i * 16 + lrow;
        aoff[i] = rowa * 32 + ((q ^ ((rowa >> 1) & 3)) << 3);
    }
#pragma unroll
    for (int i = 0; i < 4; i++) {
        int rowb = wc * 64 + i * 16 + lrow;
        boff[i] = rowb * 32 + ((q ^ ((rowb >> 1) & 3)) << 3);
    }

    auto stage = [&](int it, int buf) {
        int k0 = it << 5;
#pragma unroll
        for (int i = 0; i < ASL; i++) gl2lds16(Ar[i] + k0, &As[buf * ABUF + sA[i] * 8]);
#pragma unroll
        for (int i = 0; i < 2; i++) gl2lds16(Br[i] + k0, &Bs[buf * 4096 + sB[i] * 8]);
    };

    int nk = K >> 5;
    stage(0, 0);
    stage(1, 1);
    int cur = 0;
    for (int it = 0; it < nk; it++) {
        if (it + 1 < nk) __builtin_amdgcn_s_waitcnt(WVM);
        else             __builtin_amdgcn_s_waitcnt(0x0F70);
        __builtin_amdgcn_s_barrier();
        int nxt = cur + 2; if (nxt >= 3) nxt -= 3;
        if (it + 2 < nk) stage(it + 2, nxt);

        f16x8 af[MFRAG], bf[4];
#pragma unroll
        for (int i = 0; i < MFRAG; i++) af[i] = *(const f16x8*)&As[cur * ABUF + aoff[i]];
#pragma unroll
        for (int i = 0; i < 4; i++) bf[i] = *(const f16x8*)&Bs[cur * 4096 + boff[i]];
#pragma unroll
        for (int mt = 0; mt < MFRAG; mt++)
#pragma unroll
            for (int nt = 0; nt < 4; nt++)
                acc[mt][nt] = __builtin_amdgcn_mfma_f32_16x16x32_f16(bf[nt], af[mt], acc[mt][nt], 0, 0, 0);
        cur = (cur + 1 == 3) ? 0 : cur + 1;
    }

#pragma unroll
    for (int mt = 0; mt < MFRAG; mt++) {
        int m = m0 + wr * (MFRAG * 16) + mt * 16 + lrow;
#pragma unroll
        for (int nt = 0; nt < 4; nt++) {
            int n = n0 + wc * 64 + nt * 16 + q * 4;
            f16x4 o = {(_Float16)acc[mt][nt][0], (_Float16)acc[mt][nt][1],
                       (_Float16)acc[mt][nt][2], (_Float16)acc[mt][nt][3]};
            *(f16x4*)(C + (long)m * N + n) = o;
        }
    }

    float4 av[4], dvv[4];
#pragma unroll
    for (int nt = 0; nt < 4; nt++) {
        av[nt]  = *(const float4*)(asf + n0 + wc * 64 + nt * 16 + q * 4);
        dvv[nt] = *(const float4*)(adf + n0 + wc * 64 + nt * 16 + q * 4);
    }
    __syncthreads();
    float* sAs = (float*)smem;
    float* sAd = (float*)smem + BM * 2;
#pragma unroll
    for (int mt = 0; mt < MFRAG; mt++) {
        float ps = 0.f, pd = 0.f;
#pragma unroll
        for (int nt = 0; nt < 4; nt++) {
            ps += acc[mt][nt][0] * av[nt].x + acc[mt][nt][1] * av[nt].y
                + acc[mt][nt][2] * av[nt].z + acc[mt][nt][3] * av[nt].w;
            pd += acc[mt][nt][0] * dvv[nt].x + acc[mt][nt][1] * dvv[nt].y
                + acc[mt][nt][2] * dvv[nt].z + acc[mt][nt][3] * dvv[nt].w;
        }
        ps += __shfl_xor(ps, 16); ps += __shfl_xor(ps, 32);
        pd += __shfl_xor(pd, 16); pd += __shfl_xor(pd, 32);
        if (q == 0) {
            int rl = wr * (MFRAG * 16) + mt * 16 + lrow;
            sAs[rl * 2 + wc] = ps;
            sAd[rl * 2 + wc] = pd;
        }
    }
    __syncthreads();
    if (t < BM) {
        int m = m0 + t;
        if (m < NN) {
            int hb = n0 / headw;
            if (headw == 128) {
                as[m * NH + hb] = sAs[t * 2] + sAs[t * 2 + 1];
                ad[m * NH + hb] = sAd[t * 2] + sAd[t * 2 + 1];
            } else {
                as[m * NH + hb]     = sAs[t * 2];
                as[m * NH + hb + 1] = sAs[t * 2 + 1];
                ad[m * NH + hb]     = sAd[t * 2];
                ad[m * NH + hb + 1] = sAd[t * 2 + 1];
            }
        }
    }
}

// ---------------- layer-1 agg: no-max softmax + 8-deep gather pipeline ----------------
// exp without max-subtraction is exact here (|logit| << 80); kills 12 shuffle
// rounds/block and one edge pass in the rare deg>64 path.
__global__ __launch_bounds__(320) void k_agg1(const int* __restrict__ cnt,
                                              const int* __restrict__ bucket,
                                              const float* __restrict__ as,
                                              const float* __restrict__ ad,
                                              const _Float16* __restrict__ h,
                                              const float* __restrict__ bias,
                                              _Float16* __restrict__ A2) {
    __shared__ int sidx[64];
    __shared__ float sal[64 * NH];
    int n = blockIdx.x, t = threadIdx.x;
    if (n >= NN) {
        f16x4 z = {(_Float16)0.f, (_Float16)0.f, (_Float16)0.f, (_Float16)0.f};
        *(f16x4*)(A2 + (long)n * HC1 + 4 * t) = z;
        return;
    }
    int deg = min(cnt[n], CAP);
    const int* bkt = bucket + (long)n * CAP;
    int w = t >> 6, lane = t & 63;
    int hd = t >> 5;
    float acc[4] = {0, 0, 0, 0};

    if (deg <= 64) {
        int src = (lane < deg) ? bkt[lane] : 0;
        float2 adv = *(const float2*)(ad + n * NH + 2 * w);
        float x0 = 0.f, x1 = 0.f;
        if (lane < deg) {
            float2 avv = *(const float2*)(as + (long)src * NH + 2 * w);
            x0 = __expf(leaky(avv.x + adv.x));
            x1 = __expf(leaky(avv.y + adv.y));
        }
        float s0 = x0, s1 = x1;
        for (int m = 32; m; m >>= 1) {
            s0 += __shfl_xor(s0, m);
            s1 += __shfl_xor(s1, m);
        }
        if (lane < deg) {
            sal[lane * NH + 2 * w]     = x0 / (s0 + 1e-16f);
            sal[lane * NH + 2 * w + 1] = x1 / (s1 + 1e-16f);
            if (w == 0) sidx[lane] = src;
        }
        __syncthreads();
        int j = 0;
        for (; j + 8 <= deg; j += 8) {            // 8 loads in flight
            int sj[8]; float aa[8];
#pragma unroll
            for (int u = 0; u < 8; u++) { sj[u] = sidx[j + u]; aa[u] = sal[(j + u) * NH + hd]; }
            f16x4 vv[8];
#pragma unroll
            for (int u = 0; u < 8; u++) vv[u] = *(const f16x4*)(h + (long)sj[u] * HC1 + 4 * t);
#pragma unroll
            for (int i = 0; i < 4; i++) {
                float s = 0.f;
#pragma unroll
                for (int u = 0; u < 8; u++) s += aa[u] * (float)vv[u][i];
                acc[i] += s;
            }
        }
        for (; j + 4 <= deg; j += 4) {
            int sj0 = sidx[j], sj1 = sidx[j + 1], sj2 = sidx[j + 2], sj3 = sidx[j + 3];
            float a0 = sal[j * NH + hd], a1 = sal[(j + 1) * NH + hd];
            float a2 = sal[(j + 2) * NH + hd], a3 = sal[(j + 3) * NH + hd];
            f16x4 v0 = *(const f16x4*)(h + (long)sj0 * HC1 + 4 * t);
            f16x4 v1 = *(const f16x4*)(h + (long)sj1 * HC1 + 4 * t);
            f16x4 v2 = *(const f16x4*)(h + (long)sj2 * HC1 + 4 * t);
            f16x4 v3 = *(const f16x4*)(h + (long)sj3 * HC1 + 4 * t);
#pragma unroll
            for (int i = 0; i < 4; i++)
                acc[i] += a0 * (float)v0[i] + a1 * (float)v1[i]
                        + a2 * (float)v2[i] + a3 * (float)v3[i];
        }
        for (; j < deg; j++) {
            int src2 = sidx[j];
            float a = sal[j * NH + hd];
            f16x4 v = *(const f16x4*)(h + (long)src2 * HC1 + 4 * t);
#pragma unroll
            for (int i = 0; i < 4; i++) acc[i] += a * (float)v[i];
        }
    } else {
        float2 adv = *(const float2*)(ad + n * NH + 2 * w);
        float s0 = 0.f, s1 = 0.f;
        for (int j = lane; j < deg; j += 64) {
            float2 avv = *(const float2*)(as + (long)bkt[j] * NH + 2 * w);
            s0 += __expf(leaky(avv.x + adv.x));
            s1 += __expf(leaky(avv.y + adv.y));
        }
        for (int m = 32; m; m >>= 1) {
            s0 += __shfl_xor(s0, m);
            s1 += __shfl_xor(s1, m);
        }
        float i0 = 1.f / (s0 + 1e-16f), i1 = 1.f / (s1 + 1e-16f);
        for (int c0 = 0; c0 < deg; c0 += 64) {
            int cn = min(64, deg - c0);
            __syncthreads();
            if (lane < cn) {
                int src = bkt[c0 + lane];
                float2 avv = *(const float2*)(as + (long)src * NH + 2 * w);
                sal[lane * NH + 2 * w]     = __expf(leaky(avv.x + adv.x)) * i0;
                sal[lane * NH + 2 * w + 1] = __expf(leaky(avv.y + adv.y)) * i1;
                if (w == 0) sidx[lane] = src;
            }
            __syncthreads();
            for (int j = 0; j < cn; j++) {
                int src2 = sidx[j];
                float a = sal[j * NH + hd];
                f16x4 v = *(const f16x4*)(h + (long)src2 * HC1 + 4 * t);
#pragma unroll
                for (int i = 0; i < 4; i++) acc[i] += a * (float)v[i];
            }
        }
    }
    f16x4 o;
#pragma unroll
    for (int i = 0; i < 4; i++) {
        float x = acc[i] + bias[4 * t + i];
        o[i] = (_Float16)(x > 0.f ? x : 0.f);
    }
    *(f16x4*)(A2 + (long)n * HC1 + 4 * t) = o;
}

// ---------------- layer-2 agg: no-max softmax + 8-deep gather + head mean ----------------
__global__ __launch_bounds__(320) void k_agg2(const int* __restrict__ cnt,
                                              const int* __restrict__ bucket,
                                              const float* __restrict__ as,
                                              const float* __restrict__ ad,
                                              const _Float16* __restrict__ h,
                                              const float* __restrict__ bias,
                                              float* __restrict__ out) {
    __shared__ int sidx[64];
    __shared__ float sal[64 * NH];
    __shared__ float facc[HC2];
    int n = blockIdx.x, t = threadIdx.x;
    int deg = min(cnt[n], CAP);
    const int* bkt = bucket + (long)n * CAP;
    int w = t >> 6, lane = t & 63;
    int hd = t >> 5;
    float a0 = 0.f, a1 = 0.f;

    if (deg <= 64) {
        int src = (lane < deg) ? bkt[lane] : 0;
        float2 adv = *(const float2*)(ad + n * NH + 2 * w);
        float x0 = 0.f, x1 = 0.f;
        if (lane < deg) {
            float2 avv = *(const float2*)(as + (long)src * NH + 2 * w);
            x0 = __expf(leaky(avv.x + adv.x));
            x1 = __expf(leaky(avv.y + adv.y));
        }
        float s0 = x0, s1 = x1;
        for (int m = 32; m; m >>= 1) {
            s0 += __shfl_xor(s0, m);
            s1 += __shfl_xor(s1, m);
        }
        if (lane < deg) {
            sal[lane * NH + 2 * w]     = x0 / (s0 + 1e-16f);
            sal[lane * NH + 2 * w + 1] = x1 / (s1 + 1e-16f);
            if (w == 0) sidx[lane] = src;
        }
        __syncthreads();
        int j = 0;
        for (; j + 8 <= deg; j += 8) {            // 8 loads in flight
            int sj[8]; float aa[8];
#pragma unroll
            for (int u = 0; u < 8; u++) { sj[u] = sidx[j + u]; aa[u] = sal[(j + u) * NH + hd]; }
            f16x2 vv[8];
#pragma unroll
            for (int u = 0; u < 8; u++) vv[u] = *(const f16x2*)(h + (long)sj[u] * HC2 + 2 * t);
            float p0 = 0.f, p1 = 0.f;
#pragma unroll
            for (int u = 0; u < 8; u++) { p0 += aa[u] * (float)vv[u][0]; p1 += aa[u] * (float)vv[u][1]; }
            a0 += p0; a1 += p1;
        }
        for (; j + 4 <= deg; j += 4) {
            int sj0 = sidx[j], sj1 = sidx[j + 1], sj2 = sidx[j + 2], sj3 = sidx[j + 3];
            float b0 = sal[j * NH + hd], b1 = sal[(j + 1) * NH + hd];
            float b2 = sal[(j + 2) * NH + hd], b3 = sal[(j + 3) * NH + hd];
            f16x2 v0 = *(const f16x2*)(h + (long)sj0 * HC2 + 2 * t);
            f16x2 v1 = *(const f16x2*)(h + (long)sj1 * HC2 + 2 * t);
            f16x2 v2 = *(const f16x2*)(h + (long)sj2 * HC2 + 2 * t);
            f16x2 v3 = *(const f16x2*)(h + (long)sj3 * HC2 + 2 * t);
            a0 += b0 * (float)v0[0] + b1 * (float)v1[0] + b2 * (float)v2[0] + b3 * (float)v3[0];
            a1 += b0 * (float)v0[1] + b1 * (float)v1[1] + b2 * (float)v2[1] + b3 * (float)v3[1];
        }
        for (; j < deg; j++) {
            int src2 = sidx[j];
            float a = sal[j * NH + hd];
            f16x2 v = *(const f16x2*)(h + (long)src2 * HC2 + 2 * t);
            a0 += a * (float)v[0];
            a1 += a * (float)v[1];
        }
    } else {
        float2 adv = *(const float2*)(ad + n * NH + 2 * w);
        float s0 = 0.f, s1 = 0.f;
        for (int j = lane; j < deg; j += 64) {
            float2 avv = *(const float2*)(as + (long)bkt[j] * NH + 2 * w);
            s0 += __expf(leaky(avv.x + adv.x));
            s1 += __expf(leaky(avv.y + adv.y));
        }
        for (int m = 32; m; m >>= 1) {
            s0 += __shfl_xor(s0, m);
            s1 += __shfl_xor(s1, m);
        }
        float i0 = 1.f / (s0 + 1e-16f), i1 = 1.f / (s1 + 1e-16f);
        for (int c0 = 0; c0 < deg; c0 += 64) {
            int cn = min(64, deg - c0);
            __syncthreads();
            if (lane < cn) {
                int src = bkt[c0 + lane];
                float2 avv = *(const float2*)(as + (long)src * NH + 2 * w);
                sal[lane * NH + 2 * w]     = __expf(leaky(avv.x + adv.x)) * i0;
                sal[lane * NH + 2 * w + 1] = __expf(leaky(avv.y + adv.y)) * i1;
                if (w == 0) sidx[lane] = src;
            }
            __syncthreads();
            for (int j = 0; j < cn; j++) {
                int src2 = sidx[j];
                float a = sal[j * NH + hd];
                f16x2 v = *(const f16x2*)(h + (long)src2 * HC2 + 2 * t);
                a0 += a * (float)v[0];
                a1 += a * (float)v[1];
            }
        }
    }
    facc[2 * t] = a0;
    facc[2 * t + 1] = a1;
    __syncthreads();
    if (t < C2) {
        float s = 0.f;
#pragma unroll
        for (int hh = 0; hh < NH; hh++) s += facc[hh * C2 + t];
        s = s * 0.1f + bias[t];
        out[(long)n * C2 + t] = s > 0.f ? s : 0.f;
    }
}

// ---------------- host ----------------
extern "C" void kernel_launch(void* const* d_in, const int* in_sizes, int n_in,
                              void* d_out, int out_size, void* d_ws, size_t ws_size,
                              hipStream_t stream) {
    const float* x      = (const float*)d_in[0];
    const int*   ei     = (const int*)d_in[1];
    const float* W1     = (const float*)d_in[2];
    const float* asrc1  = (const float*)d_in[3];
    const float* adst1  = (const float*)d_in[4];
    const float* b1     = (const float*)d_in[5];
    const float* W2     = (const float*)d_in[6];
    const float* asrc2  = (const float*)d_in[7];
    const float* adst2  = (const float*)d_in[8];
    const float* b2     = (const float*)d_in[9];
    float* out = (float*)d_out;
    const int E  = in_sizes[1] / 2;

    char* base = (char*)d_ws;
    size_t o = 0;
    auto alloc = [&](size_t bytes) { size_t r = o; o += (bytes + 255) & ~(size_t)255; return r; };
    _Float16* A1    = (_Float16*)(base + alloc((size_t)MP * K1P * 2));
    _Float16* W1t   = (_Float16*)(base + alloc((size_t)HC1 * K1P * 2));
    _Float16* A2    = (_Float16*)(base + alloc((size_t)MP * HC1 * 2));
    _Float16* W2t   = (_Float16*)(base + alloc((size_t)HC2 * HC1 * 2));
    _Float16* h1pre = (_Float16*)(base + alloc((size_t)MP * HC1 * 2));
    _Float16* h2pre = (_Float16*)(base + alloc((size_t)MP * HC2 * 2));
    float* as1      = (float*)(base + alloc((size_t)NN * NH * 4));
    float* ad1      = (float*)(base + alloc((size_t)NN * NH * 4));
    float* as2      = (float*)(base + alloc((size_t)NN * NH * 4));
    float* ad2      = (float*)(base + alloc((size_t)NN * NH * 4));
    int* cnt        = (int*)(base + alloc((size_t)NN * 4));
    int* bucket     = (int*)(base + alloc((size_t)NN * CAP * 4));
    (void)ws_size; (void)n_in; (void)out_size;

    const int FILLB = (E + NN + 511) / 512;            // 512-thr fill side blocks
    const int W2TB  = (40 * 20) / 2;                   // 400 dual-tile W2t side blocks
    const int G1 = 8 * (MP / 256 / 8) * (HC1 / 256);   // 200 gemm1 blocks (256x256)
    const int G2 = 8 * (MP / 256 / 8) * (HC2 / 128);   // 200 gemm2 blocks (MFRAG=8)

    // ---- zero cnt; prep = cast + W1 transpose only ----
    hipMemsetAsync(cnt, 0, (size_t)NN * 4, stream);
    k_prep<<<NCAST + NW1, 256, 0, stream>>>(x, A1, W1, W1t);
    // ---- layer 1 GEMM + side-jobs (bucket fill, W2 transpose) on idle CUs ----
    k_gemm1<<<G1 + FILLB + W2TB, 512, 0, stream>>>(A1, W1t, h1pre, asrc1, adst1, as1, ad1,
                                                   W2, W2t, ei, cnt, bucket, E, G1, FILLB);
    // ---- layer 1 agg ----
    k_agg1<<<MP, 320, 0, stream>>>(cnt, bucket, as1, ad1, h1pre, b1, A2);
    // ---- layer 2 GEMM (MFRAG=8, 200 blocks) ----
    k_gemm<8><<<G2, 256, 0, stream>>>(A2, W2t, h2pre, HC1, HC2, HC2 / 128,
                                      asrc2, adst2, as2, ad2, C2);
    // ---- layer 2 agg ----
    k_agg2<<<NN, 320, 0, stream>>>(cnt, bucket, as2, ad2, h2pre, b2, out);
}